// Round 21
// baseline (74.720 us; speedup 1.0000x reference)
//
#include <hip/hip_runtime.h>
#include <math.h>

#define BB 4
#define CC 256
#define HH 64
#define WW 64
#define HW 4096
#define XTR 4240   // padded rows per batch: 72 + 4096 + 72
#define XPAD 72

typedef __attribute__((ext_vector_type(8))) _Float16 half8;
typedef __attribute__((ext_vector_type(4))) _Float16 half4;
typedef __attribute__((ext_vector_type(4))) float f32x4;

__device__ inline void gld16(const void* g, void* l) {
    __builtin_amdgcn_global_load_lds((const __attribute__((address_space(1))) void*)g,
                                     (__attribute__((address_space(3))) void*)l, 16, 0, 0);
}

// ---------------- K1: fused prep: xt (bilinear+transpose), pad rows, W2, W3T ---------
// W3T: BK=64 staging tiles [ot 2][ks 36][r 128][q 8] of 8 halfs; slot (r,q) holds
// source chunk (q ^ (r&7)) of K-range [ks*64, ks*64+64).
__global__ __launch_bounds__(256) void prep_kernel(
    const float* __restrict__ tmpl, const float* __restrict__ search,
    const float* __restrict__ ow, const float* __restrict__ mw,
    const float* __restrict__ dw,
    _Float16* __restrict__ XT, _Float16* __restrict__ W2, _Float16* __restrict__ W3T) {
    int blk = blockIdx.x;
    int tid = threadIdx.x;
    __shared__ _Float16 ts[64 * 72];
    __shared__ float ts2[64 * 64];   // [c 64][row 2][w 32] f32 staging for tmpl path

    if (blk < 2048) {
        int ct = blk & 7, y = (blk >> 3) & 63, b = blk >> 9;
        if (ct >= 4) {
            const float* sp = search + ((size_t)(b * CC + (ct - 4) * 64) * HW) + y * 64;
#pragma unroll
            for (int it = 0; it < 4; ++it) {
                int c_l = it * 16 + (tid >> 4);
                int x4 = tid & 15;
                float4 v = *(const float4*)(sp + (size_t)c_l * HW + x4 * 4);
                half4 h;
                h.x = (_Float16)v.x; h.y = (_Float16)v.y;
                h.z = (_Float16)v.z; h.w = (_Float16)v.w;
                *(half4*)&ts[c_l * 72 + x4 * 4] = h;
            }
        } else {
            float sy = 0.5f * (float)y - 0.25f;
            float fy = floorf(sy);
            float wy = sy - fy;
            int y0 = (int)fy;
            int y0c = min(max(y0, 0), 31), y1c = min(max(y0 + 1, 0), 31);
            const float* tp0 = tmpl + ((size_t)(b * CC + ct * 64) * 1024);
            // stage the two needed tmpl rows for all 64 channels (coalesced float4)
#pragma unroll
            for (int j = 0; j < 4; ++j) {
                int idx = j * 256 + tid;
                int c_l = idx >> 4;
                int row = (idx >> 3) & 1;
                int w4 = idx & 7;
                const float* src = tp0 + (size_t)c_l * 1024 + (row ? y1c : y0c) * 32 + w4 * 4;
                *(float4*)&ts2[c_l * 64 + row * 32 + w4 * 4] = *(const float4*)src;
            }
            __syncthreads();
#pragma unroll 4
            for (int it = 0; it < 16; ++it) {
                int c_l = it * 4 + (tid >> 6);
                int x = tid & 63;
                float sx = 0.5f * (float)x - 0.25f;
                float fx = floorf(sx);
                float wx = sx - fx;
                int x0 = (int)fx;
                int x0c = min(max(x0, 0), 31), x1c = min(max(x0 + 1, 0), 31);
                float v00 = ts2[c_l * 64 + x0c], v01 = ts2[c_l * 64 + x1c];
                float v10 = ts2[c_l * 64 + 32 + x0c], v11 = ts2[c_l * 64 + 32 + x1c];
                ts[c_l * 72 + x] = (_Float16)((1.f - wy) * ((1.f - wx) * v00 + wx * v01) +
                                              wy * ((1.f - wx) * v10 + wx * v11));
            }
        }
        __syncthreads();
        size_t rowbase = (size_t)b * XTR + XPAD + (size_t)y * 64;
        for (int it = 0; it < 2; ++it) {
            int idx = it * 256 + tid;
            int x = idx >> 3, w = idx & 7;
            half8 o;
#pragma unroll
            for (int j = 0; j < 8; ++j) o[j] = ts[(w * 8 + j) * 72 + x];
            *(half8*)&XT[(rowbase + x) * 512 + ct * 64 + ((w ^ (x & 7)) * 8)] = o;
        }
    } else if (blk < 2192) {
        int idx = (blk - 2048) * 256 + tid;  // 36864 = 4*144*64
        int w = idx & 63;
        int r = (idx >> 6) % 144;
        int b = idx / 9216;
        int pr = (r < 72) ? r : (r + 4096);
        half8 z = {};
        *(half8*)&XT[((size_t)b * XTR + pr) * 512 + w * 8] = z;
    } else if (blk < 2264) {
        int idx = (blk - 2192) * 256 + tid;  // 18432
        int q = idx & 7;
        int oc = (idx >> 3) & 31;
        int tap = (idx >> 8) % 9;
        int ch = idx / 2304;
        int c0 = ch * 64 + (q ^ (oc & 7)) * 8;
        half8 o;
#pragma unroll
        for (int j = 0; j < 8; ++j) {
            int c = c0 + j;
            float v = 0.f;
            if (oc < 18) v = ow[((size_t)oc * 512 + c) * 9 + tap];
            else if (oc < 27 && tap == 4) v = mw[(size_t)(oc - 18) * 512 + c];
            o[j] = (_Float16)v;
        }
        *(half8*)&W2[(size_t)idx * 8] = o;
    } else {
        int g = (blk - 2264) * 256 + tid;  // 73728 chunks
        int ot = g / 36864;
        int rem = g - ot * 36864;
        int ks = rem >> 10;      // 0..35
        int ci = rem & 1023;
        int r = ci >> 3, q = ci & 7;
        int qs = q ^ (r & 7);
        int o_ = ot * 128 + r;
        int kc0 = ks * 64 + qs * 8;
        half8 o;
#pragma unroll
        for (int j = 0; j < 8; ++j) {
            int kc = kc0 + j;
            int k = kc >> 8, c = kc & 255;
            o[j] = (_Float16)dw[((size_t)o_ * CC + c) * 9 + k];
        }
        *(half8*)&W3T[(size_t)g * 8] = o;
    }
}

// ---------------- K2: fused offset/mask MFMA conv + bilinear gather -> ST2 -----------
// grid 256 = (b, 64-px tile), 512 threads. XCD-aware bijective swizzle: XCD x owns 32
// consecutive tiles of one batch (~2.1 MB <= 4 MB L2). Phase A K-SPLIT across wave
// groups; phase B gather -> ST2. B_s padded to 1600 chunks (wave-rounded gld16 tail).
__global__ __launch_bounds__(512) void offsample_kernel(
    const _Float16* __restrict__ XT, const _Float16* __restrict__ W2,
    const float* __restrict__ ob, const float* __restrict__ mb,
    _Float16* __restrict__ ST2) {
    int orig = blockIdx.x;
    int blk = ((orig & 7) << 5) + (orig >> 3);   // bijective for grid 256
    int b = blk >> 6, pt = blk & 63;
    int p0 = pt * 64;
    int tid = threadIdx.x, wave = tid >> 6, lane = tid & 63;
    int l15 = lane & 15, kq = lane >> 4;
    int grp = wave >> 2;       // 0 or 1
    int w4 = wave & 3;
    int tid256 = tid & 255;

    __shared__ __align__(16) char smem[124928];                // 2 x 62464
    _Float16* A_s = (_Float16*)(smem + grp * 62464);           // 36864 B each
    _Float16* B_s = (_Float16*)(smem + grp * 62464 + 36864);   // 24832 B + 768 B pad
    float* red_s = (float*)smem;             // 8192 B  (aliases A_s0, after barrier)
    float* offs_s = (float*)(smem + 8192);   // 6912 B
    ushort4* r4 = (ushort4*)(smem + 15104);  // 4608 B
    float4* wg4 = (float4*)(smem + 19712);   // 9216 B  (ends 28928 < 36864)

    f32x4 acc[2];
    acc[0] = (f32x4){0.f, 0.f, 0.f, 0.f};
    acc[1] = (f32x4){0.f, 0.f, 0.f, 0.f};

    const char* xrow = (const char*)(XT + ((size_t)b * XTR + XPAD + p0 - 65) * 512);
    half8 z8 = {};
    int x_ = w4 * 16 + l15;

    // ---- phase A: offmask GEMM, 4 chunk-iterations, both groups concurrent ----
    for (int ch4 = 0; ch4 < 4; ++ch4) {
        int ch = grp * 4 + ch4;
        __syncthreads();
        const char* srcA = (const char*)W2 + (size_t)ch * 36864;
#pragma unroll
        for (int it = 0; it < 9; ++it) {
            int b16 = it * 256 + w4 * 64;
            gld16(srcA + (size_t)(b16 + lane) * 16, (char*)A_s + b16 * 16);
        }
#pragma unroll
        for (int it = 0; it < 7; ++it) {
            int b16 = it * 256 + w4 * 64;
            if (b16 < 1552) {
                int c16 = b16 + lane;
                int r_u = c16 >> 3, q = c16 & 7;
                gld16(xrow + (size_t)r_u * 1024 + ch * 128 + q * 16, (char*)B_s + b16 * 16);
            }
        }
        __syncthreads();

#pragma unroll
        for (int tap = 0; tap < 9; ++tap) {
            int ky = tap / 3 - 1, kx = tap % 3 - 1;
            int dlt = ky * 64 + kx;
            int key = (l15 + dlt + 72) & 7;
            bool iv0 = (kx == -1 && x_ == 0) || (kx == 1 && x_ == 63);
            int r0 = w4 * 16 + l15 + 65 + dlt;
#pragma unroll
            for (int ks = 0; ks < 2; ++ks) {
                int qa = ((ks * 4 + kq) ^ (l15 & 7)) * 8;
                int qb = ((ks * 4 + kq) ^ key) * 8;
                half8 fa0 = *(const half8*)&A_s[tap * 2048 + l15 * 64 + qa];
                half8 fa1 = *(const half8*)&A_s[tap * 2048 + (16 + l15) * 64 + qa];
                half8 fb0 = *(const half8*)&B_s[r0 * 64 + qb];
                if (iv0) fb0 = z8;
                acc[0] = __builtin_amdgcn_mfma_f32_16x16x32_f16(fa0, fb0, acc[0], 0, 0, 0);
                acc[1] = __builtin_amdgcn_mfma_f32_16x16x32_f16(fa1, fb0, acc[1], 0, 0, 0);
            }
        }
    }

    // ---- cross-group reduction + bias/sigmoid into offs_s ----
    __syncthreads();   // all MFMAs done; A_s0 region safe to alias
    if (grp == 1) {
#pragma unroll
        for (int m = 0; m < 2; ++m)
#pragma unroll
            for (int r = 0; r < 4; ++r)
                red_s[(m * 4 + r) * 256 + tid256] = acc[m][r];
    }
    __syncthreads();
    if (grp == 0) {
#pragma unroll
        for (int m = 0; m < 2; ++m) {
#pragma unroll
            for (int r = 0; r < 4; ++r) {
                int oc = m * 16 + kq * 4 + r;
                float v = acc[m][r] + red_s[(m * 4 + r) * 256 + tid256];
                if (oc < 18) {
                    offs_s[oc * 64 + x_] = v + ob[oc];
                } else if (oc < 27) {
                    float s = v + mb[oc - 18];
                    offs_s[oc * 64 + x_] = 1.f / (1.f + expf(-s));
                }
            }
        }
    }
    __syncthreads();

    // ---- bilinear params for 64 px x 9 taps ----
    for (int i = tid; i < 576; i += 512) {
        int k = i >> 6, t = i & 63;
        int p = p0 + t;
        int y = p >> 6, x = p & 63;
        float dy = offs_s[(2 * k) * 64 + t];
        float dx = offs_s[(2 * k + 1) * 64 + t];
        float m = offs_s[(18 + k) * 64 + t];
        float py = (float)(y + k / 3 - 1) + dy;
        float px = (float)(x + k % 3 - 1) + dx;
        float fy0 = floorf(py), fx0 = floorf(px);
        float wy = py - fy0, wx = px - fx0;
        int y0 = (int)fy0, x0 = (int)fx0;
        bool vy0 = (y0 >= 0) && (y0 < HH);
        bool vy1 = (y0 + 1 >= 0) && (y0 + 1 < HH);
        bool vx0 = (x0 >= 0) && (x0 < WW);
        bool vx1 = (x0 + 1 >= 0) && (x0 + 1 < WW);
        float w00 = (vy0 && vx0) ? (1.f - wy) * (1.f - wx) * m : 0.f;
        float w01 = (vy0 && vx1) ? (1.f - wy) * wx * m : 0.f;
        float w10 = (vy1 && vx0) ? wy * (1.f - wx) * m : 0.f;
        float w11 = (vy1 && vx1) ? wy * wx * m : 0.f;
        int y0c = min(max(y0, 0), HH - 1), y1c = min(max(y0 + 1, 0), HH - 1);
        int x0c = min(max(x0, 0), WW - 1), x1c = min(max(x0 + 1, 0), WW - 1);
        r4[i] = make_ushort4((ushort)(y0c * 64 + x0c), (ushort)(y0c * 64 + x1c),
                             (ushort)(y1c * 64 + x0c), (ushort)(y1c * 64 + x1c));
        wg4[i] = make_float4(w00, w01, w10, w11);
    }
    __syncthreads();

    // ---- gather + ST2 write (BK=64 tiles [b][pt128][ks36][r128][q8], swz q^(r&7)) ----
    const _Float16* xb = XT + ((size_t)b * XTR + XPAD) * 512;
    int oct = tid & 31;
    int gg64 = (4 + (oct >> 3)) * 64;  // search half: groups 4..7
    int w0 = oct & 7;
    size_t tb = ((size_t)(b * 32 + (pt >> 1))) * 36;  // 128-px tile base (ks36 units)
    int rbase = (pt & 1) * 64;

    for (int k = 0; k < 9; ++k) {
        int ks36 = k * 4 + (oct >> 3);
#pragma unroll
        for (int it = 0; it < 4; ++it) {
            int p_l = it * 16 + (tid >> 5);
            ushort4 rr = r4[k * 64 + p_l];
            float4 w = wg4[k * 64 + p_l];
            half8 c00 = *(const half8*)(xb + (size_t)rr.x * 512 + gg64 + ((w0 ^ (rr.x & 7)) * 8));
            half8 c01 = *(const half8*)(xb + (size_t)rr.y * 512 + gg64 + ((w0 ^ (rr.y & 7)) * 8));
            half8 c10 = *(const half8*)(xb + (size_t)rr.z * 512 + gg64 + ((w0 ^ (rr.z & 7)) * 8));
            half8 c11 = *(const half8*)(xb + (size_t)rr.w * 512 + gg64 + ((w0 ^ (rr.w & 7)) * 8));
            half8 o;
#pragma unroll
            for (int j = 0; j < 8; ++j) {
                float v = w.x * (float)c00[j] + w.y * (float)c01[j] +
                          w.z * (float)c10[j] + w.w * (float)c11[j];
                o[j] = (_Float16)v;
            }
            int r = rbase + p_l;
            *(half8*)&ST2[((tb + ks36) << 13) + (r * 8 + (w0 ^ (r & 7))) * 8] = o;
        }
    }
}

// ---------------- K3: f16 MFMA GEMM, 128x64 tile, BK=64, 8 waves, 3-buf depth-2 ------
// grid 512 -> 2 blocks/CU (72 KB LDS). XCD decode matches ST2 producer: XCD =
// b*2 + (pt>>5). Counted vmcnt(3) (3 loads/stage, 2 tiles in flight, never 0
// mid-loop). stage((u+2)%3, ks+2): that buffer's readers were compute(ks-1),
// retired before the barrier we just passed (same invariant as the 4-buf ring).
__global__ __launch_bounds__(512) void deform_mfma(
    const _Float16* __restrict__ W3T, const _Float16* __restrict__ ST2,
    const float* __restrict__ db, float* __restrict__ out) {
    int orig = blockIdx.x;  // 512 blocks
    int xq = orig & 7, j = orig >> 3;
    int b = xq >> 1;
    int hi = xq & 1;
    int ot = j >> 5;
    int pt = hi * 32 + (j & 31);   // 64-px tile in [0,64)
    int o0 = ot * 128, p0 = pt * 64;
    int tid = threadIdx.x;
    int wave = tid >> 6, lane = tid & 63;
    int wo = (wave & 1) * 64, wp = (wave >> 1) * 16;

    __shared__ __align__(16) _Float16 As[3][8192];  // 3 x 16 KB
    __shared__ __align__(16) _Float16 Bs[3][4096];  // 3 x 8 KB   (total 72 KB)

    f32x4 acc[4];
#pragma unroll
    for (int i = 0; i < 4; ++i) acc[i] = (f32x4){0.f, 0.f, 0.f, 0.f};

    const _Float16* Asrc = W3T + (size_t)ot * (36 * 8192);
    const _Float16* Bsrc = ST2 + ((size_t)(b * 32 + (pt >> 1))) * (36 * 8192) + (pt & 1) * 4096;
    int fr = lane & 15, kq8 = lane >> 4;

    auto stage = [&](int buf, int ks) {  // 2 A + 1 B linear gld16 per thread
#pragma unroll
        for (int t = 0; t < 2; ++t) {
            int ci = t * 512 + tid;
            gld16(Asrc + (((size_t)ks) << 13) + (size_t)ci * 8,
                  (char*)&As[buf][0] + (size_t)ci * 16);
        }
        gld16(Bsrc + (((size_t)ks) << 13) + (size_t)tid * 8,
              (char*)&Bs[buf][0] + (size_t)tid * 16);
    };

    auto compute = [&](int cur) {  // cur compile-time at every call site
        __builtin_amdgcn_s_setprio(1);
#pragma unroll
        for (int ks2 = 0; ks2 < 2; ++ks2) {
            int c8 = ks2 * 4 + kq8;
            int cho = (c8 ^ (fr & 7)) * 8;
            half8 fa[4], fb;
#pragma unroll
            for (int f = 0; f < 4; ++f)
                fa[f] = *(const half8*)&As[cur][(wo + f * 16 + fr) * 64 + cho];
            fb = *(const half8*)&Bs[cur][(wp + fr) * 64 + cho];
#pragma unroll
            for (int i = 0; i < 4; ++i)
                acc[i] = __builtin_amdgcn_mfma_f32_16x16x32_f16(fa[i], fb, acc[i], 0, 0, 0);
        }
        __builtin_amdgcn_s_setprio(0);
    };

    stage(0, 0);
    stage(1, 1);

    for (int m = 0; m < 11; ++m) {       // ks = 0..32
#pragma unroll
        for (int u = 0; u < 3; ++u) {
            int ks = m * 3 + u;
            asm volatile("s_waitcnt vmcnt(3)" ::: "memory");
            __builtin_amdgcn_s_barrier();
            asm volatile("" ::: "memory");
            compute(u);
            stage((u + 2) % 3, ks + 2);  // readers (compute ks-1) retired
        }
    }
    // epilogue: ks = 33, 34, 35 (bufs 0, 1, 2)
    asm volatile("s_waitcnt vmcnt(3)" ::: "memory");
    __builtin_amdgcn_s_barrier();
    asm volatile("" ::: "memory");
    compute(0);
    stage(2, 35);
    asm volatile("s_waitcnt vmcnt(3)" ::: "memory");
    __builtin_amdgcn_s_barrier();
    asm volatile("" ::: "memory");
    compute(1);
    asm volatile("s_waitcnt vmcnt(0)" ::: "memory");
    __builtin_amdgcn_s_barrier();
    asm volatile("" ::: "memory");
    compute(2);

    int col = lane & 15, rb = (lane >> 4) * 4;
#pragma unroll
    for (int i = 0; i < 4; ++i) {
        int o_ = o0 + wo + i * 16 + rb;
        int p_ = p0 + wp + col;
#pragma unroll
        for (int r = 0; r < 4; ++r) {
            out[((size_t)(b * CC + o_ + r)) * HW + p_] = acc[i][r] + db[o_ + r];
        }
    }
}

extern "C" void kernel_launch(void* const* d_in, const int* in_sizes, int n_in,
                              void* d_out, int out_size, void* d_ws, size_t ws_size,
                              hipStream_t stream) {
    const float* tmpl = (const float*)d_in[0];
    const float* search = (const float*)d_in[1];
    const float* ow = (const float*)d_in[2];
    const float* ob = (const float*)d_in[3];
    const float* mw = (const float*)d_in[4];
    const float* mb = (const float*)d_in[5];
    const float* dw = (const float*)d_in[6];
    const float* db = (const float*)d_in[7];
    float* out = (float*)d_out;

    _Float16* XTp = (_Float16*)d_ws;                  // 4*4240*512   = 8,683,520 h
    _Float16* W2 = XTp + (size_t)4 * XTR * 512;       // 147,456 h
    _Float16* W3T = W2 + 147456;                      // 589,824 h
    _Float16* ST2 = W3T + 589824;                     // 37,748,736 h
    // total ~94.3 MB

    prep_kernel<<<2552, 256, 0, stream>>>(tmpl, search, ow, mw, dw, XTp, W2, W3T);
    offsample_kernel<<<256, 512, 0, stream>>>(XTp, W2, ob, mb, ST2);
    deform_mfma<<<512, 512, 0, stream>>>(W3T, ST2, db, out);
}

// Round 22
// 70.946 us; speedup vs baseline: 1.0532x; 1.0532x over previous
//
#include <hip/hip_runtime.h>
#include <math.h>

#define BB 4
#define CC 256
#define HH 64
#define WW 64
#define HW 4096
#define XTR 4240   // padded rows per batch: 72 + 4096 + 72
#define XPAD 72

typedef __attribute__((ext_vector_type(8))) _Float16 half8;
typedef __attribute__((ext_vector_type(4))) _Float16 half4;
typedef __attribute__((ext_vector_type(4))) float f32x4;

__device__ inline void gld16(const void* g, void* l) {
    __builtin_amdgcn_global_load_lds((const __attribute__((address_space(1))) void*)g,
                                     (__attribute__((address_space(3))) void*)l, 16, 0, 0);
}

// ---------------- K1: fused prep: xt (bilinear+transpose), pad rows, W2, W3T ---------
// W3T: BK=64 staging tiles [ot 2][ks 36][r 128][q 8] of 8 halfs; slot (r,q) holds
// source chunk (q ^ (r&7)) of K-range [ks*64, ks*64+64).
__global__ __launch_bounds__(256) void prep_kernel(
    const float* __restrict__ tmpl, const float* __restrict__ search,
    const float* __restrict__ ow, const float* __restrict__ mw,
    const float* __restrict__ dw,
    _Float16* __restrict__ XT, _Float16* __restrict__ W2, _Float16* __restrict__ W3T) {
    int blk = blockIdx.x;
    int tid = threadIdx.x;
    __shared__ _Float16 ts[64 * 72];
    __shared__ float ts2[64 * 64];   // [c 64][row 2][w 32] f32 staging for tmpl path

    if (blk < 2048) {
        int ct = blk & 7, y = (blk >> 3) & 63, b = blk >> 9;
        if (ct >= 4) {
            const float* sp = search + ((size_t)(b * CC + (ct - 4) * 64) * HW) + y * 64;
#pragma unroll
            for (int it = 0; it < 4; ++it) {
                int c_l = it * 16 + (tid >> 4);
                int x4 = tid & 15;
                float4 v = *(const float4*)(sp + (size_t)c_l * HW + x4 * 4);
                half4 h;
                h.x = (_Float16)v.x; h.y = (_Float16)v.y;
                h.z = (_Float16)v.z; h.w = (_Float16)v.w;
                *(half4*)&ts[c_l * 72 + x4 * 4] = h;
            }
        } else {
            float sy = 0.5f * (float)y - 0.25f;
            float fy = floorf(sy);
            float wy = sy - fy;
            int y0 = (int)fy;
            int y0c = min(max(y0, 0), 31), y1c = min(max(y0 + 1, 0), 31);
            const float* tp0 = tmpl + ((size_t)(b * CC + ct * 64) * 1024);
            // stage the two needed tmpl rows for all 64 channels (coalesced float4)
#pragma unroll
            for (int j = 0; j < 4; ++j) {
                int idx = j * 256 + tid;
                int c_l = idx >> 4;
                int row = (idx >> 3) & 1;
                int w4 = idx & 7;
                const float* src = tp0 + (size_t)c_l * 1024 + (row ? y1c : y0c) * 32 + w4 * 4;
                *(float4*)&ts2[c_l * 64 + row * 32 + w4 * 4] = *(const float4*)src;
            }
            __syncthreads();
#pragma unroll 4
            for (int it = 0; it < 16; ++it) {
                int c_l = it * 4 + (tid >> 6);
                int x = tid & 63;
                float sx = 0.5f * (float)x - 0.25f;
                float fx = floorf(sx);
                float wx = sx - fx;
                int x0 = (int)fx;
                int x0c = min(max(x0, 0), 31), x1c = min(max(x0 + 1, 0), 31);
                float v00 = ts2[c_l * 64 + x0c], v01 = ts2[c_l * 64 + x1c];
                float v10 = ts2[c_l * 64 + 32 + x0c], v11 = ts2[c_l * 64 + 32 + x1c];
                ts[c_l * 72 + x] = (_Float16)((1.f - wy) * ((1.f - wx) * v00 + wx * v01) +
                                              wy * ((1.f - wx) * v10 + wx * v11));
            }
        }
        __syncthreads();
        size_t rowbase = (size_t)b * XTR + XPAD + (size_t)y * 64;
        for (int it = 0; it < 2; ++it) {
            int idx = it * 256 + tid;
            int x = idx >> 3, w = idx & 7;
            half8 o;
#pragma unroll
            for (int j = 0; j < 8; ++j) o[j] = ts[(w * 8 + j) * 72 + x];
            *(half8*)&XT[(rowbase + x) * 512 + ct * 64 + ((w ^ (x & 7)) * 8)] = o;
        }
    } else if (blk < 2192) {
        int idx = (blk - 2048) * 256 + tid;  // 36864 = 4*144*64
        int w = idx & 63;
        int r = (idx >> 6) % 144;
        int b = idx / 9216;
        int pr = (r < 72) ? r : (r + 4096);
        half8 z = {};
        *(half8*)&XT[((size_t)b * XTR + pr) * 512 + w * 8] = z;
    } else if (blk < 2264) {
        int idx = (blk - 2192) * 256 + tid;  // 18432
        int q = idx & 7;
        int oc = (idx >> 3) & 31;
        int tap = (idx >> 8) % 9;
        int ch = idx / 2304;
        int c0 = ch * 64 + (q ^ (oc & 7)) * 8;
        half8 o;
#pragma unroll
        for (int j = 0; j < 8; ++j) {
            int c = c0 + j;
            float v = 0.f;
            if (oc < 18) v = ow[((size_t)oc * 512 + c) * 9 + tap];
            else if (oc < 27 && tap == 4) v = mw[(size_t)(oc - 18) * 512 + c];
            o[j] = (_Float16)v;
        }
        *(half8*)&W2[(size_t)idx * 8] = o;
    } else {
        int g = (blk - 2264) * 256 + tid;  // 73728 chunks
        int ot = g / 36864;
        int rem = g - ot * 36864;
        int ks = rem >> 10;      // 0..35
        int ci = rem & 1023;
        int r = ci >> 3, q = ci & 7;
        int qs = q ^ (r & 7);
        int o_ = ot * 128 + r;
        int kc0 = ks * 64 + qs * 8;
        half8 o;
#pragma unroll
        for (int j = 0; j < 8; ++j) {
            int kc = kc0 + j;
            int k = kc >> 8, c = kc & 255;
            o[j] = (_Float16)dw[((size_t)o_ * CC + c) * 9 + k];
        }
        *(half8*)&W3T[(size_t)g * 8] = o;
    }
}

// ---------------- K2: fused offset/mask MFMA conv + bilinear gather -> ST2 -----------
// grid 256 = (b, 64-px tile), 512 threads. XCD-aware bijective swizzle: XCD x owns 32
// consecutive tiles of one batch (~2.1 MB <= 4 MB L2). Phase A K-SPLIT across wave
// groups; phase B gather -> ST2. B_s padded to 1600 chunks (wave-rounded gld16 tail).
__global__ __launch_bounds__(512) void offsample_kernel(
    const _Float16* __restrict__ XT, const _Float16* __restrict__ W2,
    const float* __restrict__ ob, const float* __restrict__ mb,
    _Float16* __restrict__ ST2) {
    int orig = blockIdx.x;
    int blk = ((orig & 7) << 5) + (orig >> 3);   // bijective for grid 256
    int b = blk >> 6, pt = blk & 63;
    int p0 = pt * 64;
    int tid = threadIdx.x, wave = tid >> 6, lane = tid & 63;
    int l15 = lane & 15, kq = lane >> 4;
    int grp = wave >> 2;       // 0 or 1
    int w4 = wave & 3;
    int tid256 = tid & 255;

    __shared__ __align__(16) char smem[124928];                // 2 x 62464
    _Float16* A_s = (_Float16*)(smem + grp * 62464);           // 36864 B each
    _Float16* B_s = (_Float16*)(smem + grp * 62464 + 36864);   // 24832 B + 768 B pad
    float* red_s = (float*)smem;             // 8192 B  (aliases A_s0, after barrier)
    float* offs_s = (float*)(smem + 8192);   // 6912 B
    ushort4* r4 = (ushort4*)(smem + 15104);  // 4608 B
    float4* wg4 = (float4*)(smem + 19712);   // 9216 B  (ends 28928 < 36864)

    f32x4 acc[2];
    acc[0] = (f32x4){0.f, 0.f, 0.f, 0.f};
    acc[1] = (f32x4){0.f, 0.f, 0.f, 0.f};

    const char* xrow = (const char*)(XT + ((size_t)b * XTR + XPAD + p0 - 65) * 512);
    half8 z8 = {};
    int x_ = w4 * 16 + l15;

    // ---- phase A: offmask GEMM, 4 chunk-iterations, both groups concurrent ----
    for (int ch4 = 0; ch4 < 4; ++ch4) {
        int ch = grp * 4 + ch4;
        __syncthreads();
        const char* srcA = (const char*)W2 + (size_t)ch * 36864;
#pragma unroll
        for (int it = 0; it < 9; ++it) {
            int b16 = it * 256 + w4 * 64;
            gld16(srcA + (size_t)(b16 + lane) * 16, (char*)A_s + b16 * 16);
        }
#pragma unroll
        for (int it = 0; it < 7; ++it) {
            int b16 = it * 256 + w4 * 64;
            if (b16 < 1552) {
                int c16 = b16 + lane;
                int r_u = c16 >> 3, q = c16 & 7;
                gld16(xrow + (size_t)r_u * 1024 + ch * 128 + q * 16, (char*)B_s + b16 * 16);
            }
        }
        __syncthreads();

#pragma unroll
        for (int tap = 0; tap < 9; ++tap) {
            int ky = tap / 3 - 1, kx = tap % 3 - 1;
            int dlt = ky * 64 + kx;
            int key = (l15 + dlt + 72) & 7;
            bool iv0 = (kx == -1 && x_ == 0) || (kx == 1 && x_ == 63);
            int r0 = w4 * 16 + l15 + 65 + dlt;
#pragma unroll
            for (int ks = 0; ks < 2; ++ks) {
                int qa = ((ks * 4 + kq) ^ (l15 & 7)) * 8;
                int qb = ((ks * 4 + kq) ^ key) * 8;
                half8 fa0 = *(const half8*)&A_s[tap * 2048 + l15 * 64 + qa];
                half8 fa1 = *(const half8*)&A_s[tap * 2048 + (16 + l15) * 64 + qa];
                half8 fb0 = *(const half8*)&B_s[r0 * 64 + qb];
                if (iv0) fb0 = z8;
                acc[0] = __builtin_amdgcn_mfma_f32_16x16x32_f16(fa0, fb0, acc[0], 0, 0, 0);
                acc[1] = __builtin_amdgcn_mfma_f32_16x16x32_f16(fa1, fb0, acc[1], 0, 0, 0);
            }
        }
    }

    // ---- cross-group reduction + bias/sigmoid into offs_s ----
    __syncthreads();   // all MFMAs done; A_s0 region safe to alias
    if (grp == 1) {
#pragma unroll
        for (int m = 0; m < 2; ++m)
#pragma unroll
            for (int r = 0; r < 4; ++r)
                red_s[(m * 4 + r) * 256 + tid256] = acc[m][r];
    }
    __syncthreads();
    if (grp == 0) {
#pragma unroll
        for (int m = 0; m < 2; ++m) {
#pragma unroll
            for (int r = 0; r < 4; ++r) {
                int oc = m * 16 + kq * 4 + r;
                float v = acc[m][r] + red_s[(m * 4 + r) * 256 + tid256];
                if (oc < 18) {
                    offs_s[oc * 64 + x_] = v + ob[oc];
                } else if (oc < 27) {
                    float s = v + mb[oc - 18];
                    offs_s[oc * 64 + x_] = 1.f / (1.f + expf(-s));
                }
            }
        }
    }
    __syncthreads();

    // ---- bilinear params for 64 px x 9 taps ----
    for (int i = tid; i < 576; i += 512) {
        int k = i >> 6, t = i & 63;
        int p = p0 + t;
        int y = p >> 6, x = p & 63;
        float dy = offs_s[(2 * k) * 64 + t];
        float dx = offs_s[(2 * k + 1) * 64 + t];
        float m = offs_s[(18 + k) * 64 + t];
        float py = (float)(y + k / 3 - 1) + dy;
        float px = (float)(x + k % 3 - 1) + dx;
        float fy0 = floorf(py), fx0 = floorf(px);
        float wy = py - fy0, wx = px - fx0;
        int y0 = (int)fy0, x0 = (int)fx0;
        bool vy0 = (y0 >= 0) && (y0 < HH);
        bool vy1 = (y0 + 1 >= 0) && (y0 + 1 < HH);
        bool vx0 = (x0 >= 0) && (x0 < WW);
        bool vx1 = (x0 + 1 >= 0) && (x0 + 1 < WW);
        float w00 = (vy0 && vx0) ? (1.f - wy) * (1.f - wx) * m : 0.f;
        float w01 = (vy0 && vx1) ? (1.f - wy) * wx * m : 0.f;
        float w10 = (vy1 && vx0) ? wy * (1.f - wx) * m : 0.f;
        float w11 = (vy1 && vx1) ? wy * wx * m : 0.f;
        int y0c = min(max(y0, 0), HH - 1), y1c = min(max(y0 + 1, 0), HH - 1);
        int x0c = min(max(x0, 0), WW - 1), x1c = min(max(x0 + 1, 0), WW - 1);
        r4[i] = make_ushort4((ushort)(y0c * 64 + x0c), (ushort)(y0c * 64 + x1c),
                             (ushort)(y1c * 64 + x0c), (ushort)(y1c * 64 + x1c));
        wg4[i] = make_float4(w00, w01, w10, w11);
    }
    __syncthreads();

    // ---- gather + ST2 write (BK=64 tiles [b][pt128][ks36][r128][q8], swz q^(r&7)) ----
    const _Float16* xb = XT + ((size_t)b * XTR + XPAD) * 512;
    int oct = tid & 31;
    int gg64 = (4 + (oct >> 3)) * 64;  // search half: groups 4..7
    int w0 = oct & 7;
    size_t tb = ((size_t)(b * 32 + (pt >> 1))) * 36;  // 128-px tile base (ks36 units)
    int rbase = (pt & 1) * 64;

    for (int k = 0; k < 9; ++k) {
        int ks36 = k * 4 + (oct >> 3);
#pragma unroll
        for (int it = 0; it < 4; ++it) {
            int p_l = it * 16 + (tid >> 5);
            ushort4 rr = r4[k * 64 + p_l];
            float4 w = wg4[k * 64 + p_l];
            half8 c00 = *(const half8*)(xb + (size_t)rr.x * 512 + gg64 + ((w0 ^ (rr.x & 7)) * 8));
            half8 c01 = *(const half8*)(xb + (size_t)rr.y * 512 + gg64 + ((w0 ^ (rr.y & 7)) * 8));
            half8 c10 = *(const half8*)(xb + (size_t)rr.z * 512 + gg64 + ((w0 ^ (rr.z & 7)) * 8));
            half8 c11 = *(const half8*)(xb + (size_t)rr.w * 512 + gg64 + ((w0 ^ (rr.w & 7)) * 8));
            half8 o;
#pragma unroll
            for (int j = 0; j < 8; ++j) {
                float v = w.x * (float)c00[j] + w.y * (float)c01[j] +
                          w.z * (float)c10[j] + w.w * (float)c11[j];
                o[j] = (_Float16)v;
            }
            int r = rbase + p_l;
            *(half8*)&ST2[((tb + ks36) << 13) + (r * 8 + (w0 ^ (r & 7))) * 8] = o;
        }
    }
}

// ---------------- K3: f16 MFMA GEMM, 128x128, BK=64, 8 waves, 4-buf depth-3 ----------
// XCD swizzle aligned to ST2 producers: offsample wrote tile (b,pt) from XCD
// b*2+(pt>>4); decode so this block (and its ot-sibling reading the SAME Bsrc)
// land there too -> ST2 reads become L2 hits / single-fetch.
__global__ __launch_bounds__(512) void deform_mfma(
    const _Float16* __restrict__ W3T, const _Float16* __restrict__ ST2,
    const float* __restrict__ db, float* __restrict__ out) {
    int orig = blockIdx.x;
    int xq = orig & 7, j = orig >> 3;
    int b = xq >> 1;
    int ot = j >> 4;
    int pt = ((xq & 1) << 4) + (j & 15);
    int o0 = ot * 128, p0 = pt * 128;
    int tid = threadIdx.x;
    int wave = tid >> 6, lane = tid & 63;
    int wo = (wave & 1) * 64, wp = (wave >> 1) * 32;

    __shared__ __align__(16) _Float16 As[4][8192];  // 4 x 16 KB
    __shared__ __align__(16) _Float16 Bs[4][8192];  // 4 x 16 KB  (total 128 KB)

    f32x4 acc[4][2];
#pragma unroll
    for (int i = 0; i < 4; ++i)
#pragma unroll
        for (int j2 = 0; j2 < 2; ++j2) acc[i][j2] = (f32x4){0.f, 0.f, 0.f, 0.f};

    const _Float16* Asrc = W3T + (size_t)ot * (36 * 8192);
    const _Float16* Bsrc = ST2 + ((size_t)(b * 32 + pt)) * (36 * 8192);
    int fr = lane & 15, kq8 = lane >> 4;

    auto stage = [&](int buf, int ks) {  // 2 A + 2 B linear gld16 per thread
#pragma unroll
        for (int t = 0; t < 2; ++t) {
            int ci = t * 512 + tid;
            gld16(Asrc + (((size_t)ks) << 13) + (size_t)ci * 8,
                  (char*)&As[buf][0] + (size_t)ci * 16);
        }
#pragma unroll
        for (int t = 0; t < 2; ++t) {
            int ci = t * 512 + tid;
            gld16(Bsrc + (((size_t)ks) << 13) + (size_t)ci * 8,
                  (char*)&Bs[buf][0] + (size_t)ci * 16);
        }
    };

    auto compute = [&](int cur) {  // cur compile-time at every call site
        __builtin_amdgcn_s_setprio(1);
#pragma unroll
        for (int ks2 = 0; ks2 < 2; ++ks2) {
            int c8 = ks2 * 4 + kq8;
            int cho = (c8 ^ (fr & 7)) * 8;
            half8 fa[4], fb[2];
#pragma unroll
            for (int f = 0; f < 4; ++f)
                fa[f] = *(const half8*)&As[cur][(wo + f * 16 + fr) * 64 + cho];
#pragma unroll
            for (int g = 0; g < 2; ++g)
                fb[g] = *(const half8*)&Bs[cur][(wp + g * 16 + fr) * 64 + cho];
#pragma unroll
            for (int i = 0; i < 4; ++i)
#pragma unroll
                for (int j2 = 0; j2 < 2; ++j2)
                    acc[i][j2] = __builtin_amdgcn_mfma_f32_16x16x32_f16(fa[i], fb[j2], acc[i][j2], 0, 0, 0);
        }
        __builtin_amdgcn_s_setprio(0);
    };

    stage(0, 0);
    stage(1, 1);
    stage(2, 2);

    for (int m = 0; m < 8; ++m) {        // ks = 0..31
#pragma unroll
        for (int u = 0; u < 4; ++u) {
            int ks = m * 4 + u;
            asm volatile("s_waitcnt vmcnt(8)" ::: "memory");
            __builtin_amdgcn_s_barrier();
            asm volatile("" ::: "memory");
            compute(u);
            stage((u + 3) & 3, ks + 3);  // prev iteration's buffer: readers retired
        }
    }
    // epilogue: ks = 32..35 (bufs 0..3)
    asm volatile("s_waitcnt vmcnt(8)" ::: "memory");
    __builtin_amdgcn_s_barrier();
    asm volatile("" ::: "memory");
    compute(0);
    stage(3, 35);
    asm volatile("s_waitcnt vmcnt(8)" ::: "memory");
    __builtin_amdgcn_s_barrier();
    asm volatile("" ::: "memory");
    compute(1);
    asm volatile("s_waitcnt vmcnt(4)" ::: "memory");
    __builtin_amdgcn_s_barrier();
    asm volatile("" ::: "memory");
    compute(2);
    asm volatile("s_waitcnt vmcnt(0)" ::: "memory");
    __builtin_amdgcn_s_barrier();
    asm volatile("" ::: "memory");
    compute(3);

    int col = lane & 15, rb = (lane >> 4) * 4;
#pragma unroll
    for (int i = 0; i < 4; ++i) {
        int o_ = o0 + wo + i * 16 + rb;
#pragma unroll
        for (int j2 = 0; j2 < 2; ++j2) {
            int p_ = p0 + wp + j2 * 16 + col;
#pragma unroll
            for (int r = 0; r < 4; ++r) {
                out[((size_t)(b * CC + o_ + r)) * HW + p_] = acc[i][j2][r] + db[o_ + r];
            }
        }
    }
}

extern "C" void kernel_launch(void* const* d_in, const int* in_sizes, int n_in,
                              void* d_out, int out_size, void* d_ws, size_t ws_size,
                              hipStream_t stream) {
    const float* tmpl = (const float*)d_in[0];
    const float* search = (const float*)d_in[1];
    const float* ow = (const float*)d_in[2];
    const float* ob = (const float*)d_in[3];
    const float* mw = (const float*)d_in[4];
    const float* mb = (const float*)d_in[5];
    const float* dw = (const float*)d_in[6];
    const float* db = (const float*)d_in[7];
    float* out = (float*)d_out;

    _Float16* XTp = (_Float16*)d_ws;                  // 4*4240*512   = 8,683,520 h
    _Float16* W2 = XTp + (size_t)4 * XTR * 512;       // 147,456 h
    _Float16* W3T = W2 + 147456;                      // 589,824 h
    _Float16* ST2 = W3T + 589824;                     // 37,748,736 h
    // total ~94.3 MB

    prep_kernel<<<2552, 256, 0, stream>>>(tmpl, search, ow, mw, dw, XTp, W2, W3T);
    offsample_kernel<<<256, 512, 0, stream>>>(XTp, W2, ob, mb, ST2);
    deform_mfma<<<256, 512, 0, stream>>>(W3T, ST2, db, out);
}